// Round 8
// baseline (928.943 us; speedup 1.0000x reference)
//
#include <hip/hip_runtime.h>

// ConvBlock5: pool -> conv x2 -> unpool, C=64 fp32.
// Round 7 resubmit (GPU-acquisition timeout last round; source unchanged,
// re-audited: fused-gemm lane algebra, merged-dispatch ranges, scratch
// carve-outs all verified).
//  - conv gemm fused INTO the conv gather (msg row is lane-replicated after
//    the shfl_xor reduce -> readlane gemm for both h and g operands; weights
//    in VGPRs). Removes bufB (51 MB traffic/layer) + 2 launches; gemm VALU
//    hides under TCC-bound gather waits.
//  - CSR build merged: hist x3 -> 1, place x3 -> 1, scans 9 -> 3 launches,
//    memsets 3 -> 2. 28 dispatches -> 11 (saves launch gaps, overlaps
//    independent atomic-fabric latency).
//  - distinct kernel names per stage (templates) for profile breakdown.

#define NCH 64

// ---------------------------------------------------------------------------
// Merged hist(+rank): 3 edge sets, block-range split. 4 edges/thread.
// ---------------------------------------------------------------------------
__global__ __launch_bounds__(256) void hist3_kernel(
    const int* __restrict__ d0, int* __restrict__ c0, int* __restrict__ r0,
    int n0, int b0, const int* __restrict__ d1, int* __restrict__ c1,
    int* __restrict__ r1, int n1, int b1, const int* __restrict__ d2,
    int* __restrict__ c2, int* __restrict__ r2, int n2) {
  int bid = blockIdx.x;
  const int* dst;
  int* cnt;
  int* rank;
  int nE;
  if (bid < b0) {
    dst = d0; cnt = c0; rank = r0; nE = n0;
  } else if (bid < b0 + b1) {
    bid -= b0; dst = d1; cnt = c1; rank = r1; nE = n1;
  } else {
    bid -= b0 + b1; dst = d2; cnt = c2; rank = r2; nE = n2;
  }
  int e0 = (bid * 256 + (int)threadIdx.x) * 4;
  if (e0 + 3 < nE) {
    int4 d = *(const int4*)(dst + e0);
    int r0v = atomicAdd(&cnt[d.x], 1);
    int r1v = atomicAdd(&cnt[d.y], 1);
    int r2v = atomicAdd(&cnt[d.z], 1);
    int r3v = atomicAdd(&cnt[d.w], 1);
    *(int4*)(rank + e0) = make_int4(r0v, r1v, r2v, r3v);
  } else {
    for (int e = e0; e < nE; ++e) rank[e] = atomicAdd(&cnt[dst[e]], 1);
  }
}

static __device__ __forceinline__ int wave_incl_scan(int v, int lane) {
#pragma unroll
  for (int off = 1; off < 64; off <<= 1) {
    int t = __shfl_up(v, off, 64);
    if (lane >= off) v += t;
  }
  return v;
}

// Merged scan pass 1: per-2048-block reduction, 3 sets.
__global__ __launch_bounds__(256) void scan_reduce3(
    const int* __restrict__ a0, int* __restrict__ s0, int n0, int b0,
    const int* __restrict__ a1, int* __restrict__ s1, int n1, int b1,
    const int* __restrict__ a2, int* __restrict__ s2, int n2) {
  int bid = blockIdx.x;
  const int* cnt;
  int* bsums;
  int n;
  if (bid < b0) {
    cnt = a0; bsums = s0; n = n0;
  } else if (bid < b0 + b1) {
    bid -= b0; cnt = a1; bsums = s1; n = n1;
  } else {
    bid -= b0 + b1; cnt = a2; bsums = s2; n = n2;
  }
  int base = bid * 2048 + threadIdx.x * 8;
  int s = 0;
#pragma unroll
  for (int j = 0; j < 8; ++j) {
    int idx = base + j;
    s += (idx < n) ? cnt[idx] : 0;
  }
  int lane = threadIdx.x & 63;
  int w = threadIdx.x >> 6;
#pragma unroll
  for (int off = 32; off; off >>= 1) s += __shfl_xor(s, off, 64);
  __shared__ int ws_[4];
  if (lane == 0) ws_[w] = s;
  __syncthreads();
  if (threadIdx.x == 0) bsums[bid] = ws_[0] + ws_[1] + ws_[2] + ws_[3];
}

// Merged scan pass 2: one block (64 threads) per set scans its bsums.
__global__ void scan_bsums3(int* __restrict__ s0, int b0, int* __restrict__ s1,
                            int b1, int* __restrict__ s2, int b2) {
  int* bs = (blockIdx.x == 0) ? s0 : (blockIdx.x == 1) ? s1 : s2;
  int nB = (blockIdx.x == 0) ? b0 : (blockIdx.x == 1) ? b1 : b2;
  int lane = threadIdx.x;  // 64 threads
  int carry = 0;
  for (int base = 0; base < nB; base += 64) {
    int i = base + lane;
    int orig = (i < nB) ? bs[i] : 0;
    int v = wave_incl_scan(orig, lane);
    if (i < nB) bs[i] = v - orig + carry;
    carry += __shfl(v, 63, 64);
  }
}

// Merged scan pass 3: in-place exclusive scan cnt -> rowptr, 3 sets.
__global__ __launch_bounds__(256) void scan_final3(
    int* __restrict__ a0, const int* __restrict__ s0, int n0, int b0,
    int* __restrict__ a1, const int* __restrict__ s1, int n1, int b1,
    int* __restrict__ a2, const int* __restrict__ s2, int n2) {
  int bid = blockIdx.x;
  int* cnt_rowptr;
  const int* bsums;
  int n;
  if (bid < b0) {
    cnt_rowptr = a0; bsums = s0; n = n0;
  } else if (bid < b0 + b1) {
    bid -= b0; cnt_rowptr = a1; bsums = s1; n = n1;
  } else {
    bid -= b0 + b1; cnt_rowptr = a2; bsums = s2; n = n2;
  }
  int base = bid * 2048 + threadIdx.x * 8;
  int v[8];
  int s = 0;
#pragma unroll
  for (int j = 0; j < 8; ++j) {
    int idx = base + j;
    v[j] = (idx < n) ? cnt_rowptr[idx] : 0;
    s += v[j];
  }
  int lane = threadIdx.x & 63;
  int w = threadIdx.x >> 6;
  int inc = wave_incl_scan(s, lane);
  __shared__ int wsum[4];
  if (lane == 63) wsum[w] = inc;
  __syncthreads();
  int woff = 0;
  for (int ww = 0; ww < w; ++ww) woff += wsum[ww];
  int excl = inc - s + woff + bsums[bid];
#pragma unroll
  for (int j = 0; j < 8; ++j) {
    int idx = base + j;
    if (idx <= n) cnt_rowptr[idx] = excl;
    excl += v[j];
  }
}

// Merged atomic-free placement: p = rowptr[dst] + rank, 3 sets.
__global__ __launch_bounds__(256) void place3_kernel(
    const int* __restrict__ sA0, const int* __restrict__ dA0,
    const float* __restrict__ aA0, const int* __restrict__ rpA0,
    const int* __restrict__ rkA0, int2* __restrict__ plA0, int n0, int b0,
    const int* __restrict__ sA1, const int* __restrict__ dA1,
    const float* __restrict__ aA1, const int* __restrict__ rpA1,
    const int* __restrict__ rkA1, int2* __restrict__ plA1, int n1, int b1,
    const int* __restrict__ sA2, const int* __restrict__ dA2,
    const float* __restrict__ aA2, const int* __restrict__ rpA2,
    const int* __restrict__ rkA2, int2* __restrict__ plA2, int n2) {
  int bid = blockIdx.x;
  const int *src, *dst, *rp, *rank;
  const float* attr;
  int2* payload;
  int nE;
  if (bid < b0) {
    src = sA0; dst = dA0; attr = aA0; rp = rpA0; rank = rkA0; payload = plA0;
    nE = n0;
  } else if (bid < b0 + b1) {
    bid -= b0;
    src = sA1; dst = dA1; attr = aA1; rp = rpA1; rank = rkA1; payload = plA1;
    nE = n1;
  } else {
    bid -= b0 + b1;
    src = sA2; dst = dA2; attr = aA2; rp = rpA2; rank = rkA2; payload = plA2;
    nE = n2;
  }
  int e0 = (bid * 256 + (int)threadIdx.x) * 4;
  if (e0 + 3 < nE) {
    int4 s = *(const int4*)(src + e0);
    int4 d = *(const int4*)(dst + e0);
    float4 a = *(const float4*)(attr + e0);
    int4 r = *(const int4*)(rank + e0);
    payload[rp[d.x] + r.x] = make_int2(s.x, __float_as_int(a.x));
    payload[rp[d.y] + r.y] = make_int2(s.y, __float_as_int(a.y));
    payload[rp[d.z] + r.z] = make_int2(s.z, __float_as_int(a.z));
    payload[rp[d.w] + r.w] = make_int2(s.w, __float_as_int(a.w));
  } else {
    for (int e = e0; e < nE; ++e)
      payload[rp[dst[e]] + rank[e]] = make_int2(src[e], __float_as_int(attr[e]));
  }
}

// ---------------------------------------------------------------------------
// Gather-reduce, MLP=4 (pool TAG=0 / unpool TAG=1 for profile separation).
// One wave per dst node; 16 lanes/edge, float4/lane.
// ---------------------------------------------------------------------------
template <int TAG>
__global__ __launch_bounds__(256) void gather4_t(
    const float* __restrict__ in, const int* __restrict__ rowptr,
    const int2* __restrict__ payload, float* __restrict__ out, int nDst) {
  const int wid = (blockIdx.x * blockDim.x + threadIdx.x) >> 6;
  const int lane = threadIdx.x & 63;
  if (wid >= nDst) return;
  const int beg = rowptr[wid];
  const int end = rowptr[wid + 1];
  const int g = lane >> 4;
  const int cq = (lane & 15) * 4;

  float4 acc = make_float4(0.f, 0.f, 0.f, 0.f);
  const int2 z = make_int2(0, 0);
  for (int jb = beg; jb < end; jb += 16) {
    const int j0 = jb + g, j1 = j0 + 4, j2 = j0 + 8, j3 = j0 + 12;
    int2 p0 = (j0 < end) ? payload[j0] : z;
    int2 p1 = (j1 < end) ? payload[j1] : z;
    int2 p2 = (j2 < end) ? payload[j2] : z;
    int2 p3 = (j3 < end) ? payload[j3] : z;
    float4 v0 = *(const float4*)(in + (size_t)p0.x * NCH + cq);
    float4 v1 = *(const float4*)(in + (size_t)p1.x * NCH + cq);
    float4 v2 = *(const float4*)(in + (size_t)p2.x * NCH + cq);
    float4 v3 = *(const float4*)(in + (size_t)p3.x * NCH + cq);
    const float a0 = __int_as_float(p0.y), a1 = __int_as_float(p1.y);
    const float a2 = __int_as_float(p2.y), a3 = __int_as_float(p3.y);
    acc.x = __builtin_fmaf(v0.x, a0, acc.x);
    acc.y = __builtin_fmaf(v0.y, a0, acc.y);
    acc.z = __builtin_fmaf(v0.z, a0, acc.z);
    acc.w = __builtin_fmaf(v0.w, a0, acc.w);
    acc.x = __builtin_fmaf(v1.x, a1, acc.x);
    acc.y = __builtin_fmaf(v1.y, a1, acc.y);
    acc.z = __builtin_fmaf(v1.z, a1, acc.z);
    acc.w = __builtin_fmaf(v1.w, a1, acc.w);
    acc.x = __builtin_fmaf(v2.x, a2, acc.x);
    acc.y = __builtin_fmaf(v2.y, a2, acc.y);
    acc.z = __builtin_fmaf(v2.z, a2, acc.z);
    acc.w = __builtin_fmaf(v2.w, a2, acc.w);
    acc.x = __builtin_fmaf(v3.x, a3, acc.x);
    acc.y = __builtin_fmaf(v3.y, a3, acc.y);
    acc.z = __builtin_fmaf(v3.z, a3, acc.z);
    acc.w = __builtin_fmaf(v3.w, a3, acc.w);
  }
#pragma unroll
  for (int off = 16; off <= 32; off <<= 1) {
    acc.x += __shfl_xor(acc.x, off, 64);
    acc.y += __shfl_xor(acc.y, off, 64);
    acc.z += __shfl_xor(acc.z, off, 64);
    acc.w += __shfl_xor(acc.w, off, 64);
  }
  if (g == 0) *(float4*)(out + (size_t)wid * NCH + cq) = acc;
}

// ---------------------------------------------------------------------------
// Fused conv layer: out[i,:] = h[i,:]@Wr + bias + gather_msg(i)@Wn.
// Grid-strided, one wave per node per iteration. After the shfl_xor reduce
// the msg row is replicated in every 16-lane group -> readlane broadcast
// works for g exactly like for h. Weights (128 VGPR) loaded once per wave.
// ---------------------------------------------------------------------------
template <int TAG>
__global__ __launch_bounds__(256) void conv_fused_t(
    const float* __restrict__ h, const int* __restrict__ rowptr,
    const int2* __restrict__ payload, const float* __restrict__ Wr,
    const float* __restrict__ Wn, const float* __restrict__ bias,
    float* __restrict__ out, int n) {
  const int lane = threadIdx.x & 63;

  float wr[64], wn[64];
#pragma unroll
  for (int k = 0; k < 64; ++k) {
    wr[k] = Wr[k * NCH + lane];
    wn[k] = Wn[k * NCH + lane];
  }
  const float bv = bias[lane];

  const int g = lane >> 4;
  const int cq = (lane & 15) * 4;
  const int wave = (blockIdx.x * blockDim.x + threadIdx.x) >> 6;
  const int nwaves = (gridDim.x * blockDim.x) >> 6;
  const int2 z = make_int2(0, 0);

  for (int i = wave; i < n; i += nwaves) {
    const int beg = rowptr[i];
    const int end = rowptr[i + 1];
    float4 acc = make_float4(0.f, 0.f, 0.f, 0.f);
    for (int jb = beg; jb < end; jb += 16) {
      const int j0 = jb + g, j1 = j0 + 4, j2 = j0 + 8, j3 = j0 + 12;
      int2 p0 = (j0 < end) ? payload[j0] : z;
      int2 p1 = (j1 < end) ? payload[j1] : z;
      int2 p2 = (j2 < end) ? payload[j2] : z;
      int2 p3 = (j3 < end) ? payload[j3] : z;
      float4 v0 = *(const float4*)(h + (size_t)p0.x * NCH + cq);
      float4 v1 = *(const float4*)(h + (size_t)p1.x * NCH + cq);
      float4 v2 = *(const float4*)(h + (size_t)p2.x * NCH + cq);
      float4 v3 = *(const float4*)(h + (size_t)p3.x * NCH + cq);
      const float a0 = __int_as_float(p0.y), a1 = __int_as_float(p1.y);
      const float a2 = __int_as_float(p2.y), a3 = __int_as_float(p3.y);
      acc.x = __builtin_fmaf(v0.x, a0, acc.x);
      acc.y = __builtin_fmaf(v0.y, a0, acc.y);
      acc.z = __builtin_fmaf(v0.z, a0, acc.z);
      acc.w = __builtin_fmaf(v0.w, a0, acc.w);
      acc.x = __builtin_fmaf(v1.x, a1, acc.x);
      acc.y = __builtin_fmaf(v1.y, a1, acc.y);
      acc.z = __builtin_fmaf(v1.z, a1, acc.z);
      acc.w = __builtin_fmaf(v1.w, a1, acc.w);
      acc.x = __builtin_fmaf(v2.x, a2, acc.x);
      acc.y = __builtin_fmaf(v2.y, a2, acc.y);
      acc.z = __builtin_fmaf(v2.z, a2, acc.z);
      acc.w = __builtin_fmaf(v2.w, a2, acc.w);
      acc.x = __builtin_fmaf(v3.x, a3, acc.x);
      acc.y = __builtin_fmaf(v3.y, a3, acc.y);
      acc.z = __builtin_fmaf(v3.z, a3, acc.z);
      acc.w = __builtin_fmaf(v3.w, a3, acc.w);
    }
#pragma unroll
    for (int off = 16; off <= 32; off <<= 1) {
      acc.x += __shfl_xor(acc.x, off, 64);
      acc.y += __shfl_xor(acc.y, off, 64);
      acc.z += __shfl_xor(acc.z, off, 64);
      acc.w += __shfl_xor(acc.w, off, 64);
    }
    // msg row now replicated: lane (k>>2) (mod 16-group) holds channels
    // 4*(k>>2).. in acc.x..w. Fused dual gemm via readlane broadcast.
    float hv = h[(size_t)i * NCH + lane];
    float o = bv;
#pragma unroll
    for (int k = 0; k < 64; ++k) {
      const int q = k >> 2;
      const float gcomp = ((k & 3) == 0)   ? acc.x
                          : ((k & 3) == 1) ? acc.y
                          : ((k & 3) == 2) ? acc.z
                                           : acc.w;
      o = __builtin_fmaf(
          __uint_as_float(__builtin_amdgcn_readlane(__float_as_uint(hv), k)),
          wr[k], o);
      o = __builtin_fmaf(
          __uint_as_float(__builtin_amdgcn_readlane(__float_as_uint(gcomp), q)),
          wn[k], o);
    }
    out[(size_t)i * NCH + lane] = o;
  }
}

extern "C" void kernel_launch(void* const* d_in, const int* in_sizes, int n_in,
                              void* d_out, int out_size, void* d_ws,
                              size_t ws_size, hipStream_t stream) {
  const float* x = (const float*)d_in[0];
  const float* W1r = (const float*)d_in[1];
  const float* W1n = (const float*)d_in[2];
  const float* b1 = (const float*)d_in[3];
  const float* W2r = (const float*)d_in[4];
  const float* W2n = (const float*)d_in[5];
  const float* b2 = (const float*)d_in[6];
  const int* pool_src = (const int*)d_in[7];
  const int* pool_dst = (const int*)d_in[8];
  const float* pool_attr = (const float*)d_in[9];
  const int* conv_src = (const int*)d_in[10];
  const int* conv_dst = (const int*)d_in[11];
  const float* conv_attr = (const float*)d_in[12];
  const int* unpool_src = (const int*)d_in[13];
  const int* unpool_dst = (const int*)d_in[14];
  const float* unpool_attr = (const float*)d_in[15];

  const int Ep = in_sizes[7];
  const int Ec = in_sizes[10];
  const int Eu = in_sizes[13];
  const int NC = 100000;  // n_coarse (fixed)
  const int NF = 400000;  // n_fine

  const size_t MiB = 1024u * 1024u;

  // ws (~37.2 MiB): bufA + unpool CSR (must survive into the final gather).
  char* ws = (char*)d_ws;
  float* bufA = (float*)ws;              // 24.4 MiB
  int* up_rp = (int*)(ws + 26 * MiB);    // 1.6 MiB (NF+1)
  int2* up_pl = (int2*)(ws + 28 * MiB);  // 9.2 MiB (Eu)

  // d_out (97.6 MiB) = scratch for everything dead before the unpool gather.
  char* ob = (char*)d_out;
  float* bufC = (float*)ob;                        // 24.4 MiB (h1)
  int* cv_rp = (int*)(ob + 26 * MiB);              // 0.4 MiB (NC+1)
  int* pl_rp = (int*)(ob + 26 * MiB + 512 * 1024); // 0.4 MiB (NC+1), adjacent
  int2* cv_pl = (int2*)(ob + 27 * MiB);            // 12.2 MiB (Ec)
  int2* pl_pl = (int2*)(ob + 40 * MiB);            // 9.2 MiB (Ep)
  int* rank_p = (int*)(ob + 50 * MiB);             // 4.6 MiB (Ep)
  int* rank_c = (int*)(ob + 55 * MiB);             // 6.1 MiB (Ec)
  int* rank_u = (int*)(ob + 62 * MiB);             // 4.6 MiB (Eu)
  int* bs_p = (int*)(ob + 67 * MiB);               // 256 ints each
  int* bs_c = bs_p + 256;
  int* bs_u = bs_c + 256;

  const dim3 blk(256);

  // Block counts for merged kernels (4 edges/thread for hist/place).
  auto eb = [](int nE) { return ((nE + 3) / 4 + 255) / 256; };
  const int hb_p = eb(Ep), hb_c = eb(Ec), hb_u = eb(Eu);
  auto sb = [](int n) { return (n + 2047) / 2048; };
  const int sb_p = sb(NC), sb_c = sb(NC), sb_u = sb(NF);

  // Zero the three rowptr/cnt arrays (cv_rp & pl_rp adjacent -> one memset).
  hipMemsetAsync(cv_rp, 0, 512 * 1024 + (size_t)(NC + 1) * sizeof(int), stream);
  hipMemsetAsync(up_rp, 0, (size_t)(NF + 1) * sizeof(int), stream);

  // CSR build: hist(+rank) -> scan -> place, all three edge sets merged.
  hist3_kernel<<<dim3(hb_p + hb_c + hb_u), blk, 0, stream>>>(
      pool_dst, pl_rp, rank_p, Ep, hb_p, conv_dst, cv_rp, rank_c, Ec, hb_c,
      unpool_dst, up_rp, rank_u, Eu);
  scan_reduce3<<<dim3(sb_p + sb_c + sb_u), blk, 0, stream>>>(
      pl_rp, bs_p, NC, sb_p, cv_rp, bs_c, NC, sb_c, up_rp, bs_u, NF);
  scan_bsums3<<<dim3(3), dim3(64), 0, stream>>>(bs_p, sb_p, bs_c, sb_c, bs_u,
                                                sb_u);
  scan_final3<<<dim3(sb_p + sb_c + sb_u), blk, 0, stream>>>(
      pl_rp, bs_p, NC, sb_p, cv_rp, bs_c, NC, sb_c, up_rp, bs_u, NF);
  place3_kernel<<<dim3(hb_p + hb_c + hb_u), blk, 0, stream>>>(
      pool_src, pool_dst, pool_attr, pl_rp, rank_p, pl_pl, Ep, hb_p, conv_src,
      conv_dst, conv_attr, cv_rp, rank_c, cv_pl, Ec, hb_c, unpool_src,
      unpool_dst, unpool_attr, up_rp, rank_u, up_pl, Eu);

  const int conv_grid = 2048;  // 8192 waves, grid-stride over 100K nodes
  const dim3 gNC((NC + 3) / 4), gNF((NF + 3) / 4);

  // 1. pool: xc = gather(x) -> bufA
  gather4_t<0><<<gNC, blk, 0, stream>>>(x, pl_rp, pl_pl, bufA, NC);

  // 2. conv1 fused: h1 = xc@W1r + b1 + gather(xc)@W1n -> bufC
  conv_fused_t<0><<<dim3(conv_grid), blk, 0, stream>>>(bufA, cv_rp, cv_pl, W1r,
                                                       W1n, b1, bufC, NC);

  // 3. conv2 fused: h2 = h1@W2r + b2 + gather(h1)@W2n -> bufA
  conv_fused_t<1><<<dim3(conv_grid), blk, 0, stream>>>(bufC, cv_rp, cv_pl, W2r,
                                                       W2n, b2, bufA, NC);

  // 4. unpool: d_out = gather(h2); writes every row (zeros for empty segs),
  //    reads only ws -> safe to overwrite all the d_out scratch.
  gather4_t<1><<<gNF, blk, 0, stream>>>(bufA, up_rp, up_pl, (float*)d_out, NF);
}